// Round 1
// baseline (265.612 us; speedup 1.0000x reference)
//
#include <hip/hip_runtime.h>

// ---------------------------------------------------------------------------
// EdgeFeatureNet: B=1, N=512, NODE_DIM=256, HID=128, EDGE_DIM=128, bins=22
//
// h1_pre[i,j] = A[i] + Bv[j] + R[i-j+511] + W1row[384+binD] + W1row[406+binS]
// h2 = relu(h1@W2+b2), h3 = h2@W3+b3, LayerNorm, * edge_mask.
//
// This version:
//  - W2/W3 pre-converted to bf16 in MFMA B-fragment layout (pre_all), read
//    directly from global (L1-resident, 32KB each) -> no weight LDS, no
//    per-block f2bf, no 8-way-conflicted ds_write_b16 staging.
//  - LDS 72KB -> 2 blocks/CU (__launch_bounds__(512,4)).
//  - Only ONE __syncthreads (bins/As); hbuf rows are wave-private.
//  - v_cvt_pk_bf16_f32 for all f32->bf16 in the hot kernel.
//  - Layer2 per-nb writeback / layer3 per-mt to keep VGPRs <= 128.
// ---------------------------------------------------------------------------

using bf16x8 = __attribute__((ext_vector_type(8))) short;
using f32x4  = __attribute__((ext_vector_type(4))) float;

__device__ __forceinline__ unsigned short f2bf(float f) {
    unsigned int u;
    __builtin_memcpy(&u, &f, 4);
    unsigned int r = (u + 0x7fffu + ((u >> 16) & 1u)) >> 16;  // RNE
    return (unsigned short)r;
}

__device__ __forceinline__ unsigned int cvt_pk_bf16(float lo, float hi) {
    unsigned int r;
    asm("v_cvt_pk_bf16_f32 %0, %1, %2" : "=v"(r) : "v"(lo), "v"(hi));
    return r;
}

// ---------------------------------------------------------------------------
// Merged pre-pass (one launch):
//   blocks [0,512):     A[i], Bv[i] (b1/flow folded)
//   blocks [512,1535):  R[d] for d+511 in [0,1023)
//   blocks [1535,1599): W2/W3 f32 -> bf16 in MFMA fragment layout
// ---------------------------------------------------------------------------
__global__ void pre_all(const float* __restrict__ nf,
                        const float* __restrict__ Wn2e,
                        const float* __restrict__ bn2e,
                        const float* __restrict__ W1,
                        const float* __restrict__ b1,
                        const float* __restrict__ flow,
                        const float* __restrict__ Wrp,
                        const float* __restrict__ brp,
                        const float* __restrict__ W2,
                        const float* __restrict__ W3,
                        float* __restrict__ A, float* __restrict__ Bv,
                        float* __restrict__ Rm,
                        short* __restrict__ W2b, short* __restrict__ W3b)
{
    __shared__ float s0[256];
    __shared__ float s1[128];
    const int bid = blockIdx.x;
    const int m = threadIdx.x;

    if (bid < 512) {
        const int i = bid;
        s0[m]       = nf[i * 256 + m];
        s0[m + 128] = nf[i * 256 + 128 + m];
        __syncthreads();
        float acc = bn2e[m];
        for (int k = 0; k < 256; k++) acc += s0[k] * Wn2e[k * 128 + m];
        s1[m] = acc;
        __syncthreads();
        const float fl = flow[i];
        float aA = b1[m] + fl * W1[428 * 128 + m];
        float aB =         fl * W1[429 * 128 + m];
        for (int k = 0; k < 128; k++) {
            const float s = s1[k];
            aA += s * W1[k * 128 + m];
            aB += s * W1[(128 + k) * 128 + m];
        }
        A[i * 128 + m]  = aA;
        Bv[i * 128 + m] = aB;
    } else if (bid < 1535) {
        const int dix = bid - 512;
        const float d = (float)(dix - 511);
        const int K = m & 63;
        const float denom = powf(2056.0f, (float)K * (1.0f / 64.0f));
        const float ang = d * 3.14159265358979323846f / denom;
        s0[m] = (m < 64) ? sinf(ang) : cosf(ang);
        __syncthreads();
        float acc = brp[m];
        for (int k = 0; k < 128; k++) acc += s0[k] * Wrp[k * 128 + m];
        s1[m] = acc;
        __syncthreads();
        float acc2 = 0.0f;
        for (int k = 0; k < 128; k++) acc2 += s1[k] * W1[(256 + k) * 128 + m];
        Rm[dix * 128 + m] = acc2;
    } else {
        // fragment layout: dst = ((k>>3)*128 + n)*8 + (k&7), idx = k*128+n
        const int t = (bid - 1535) * 128 + m;           // 0..8191
        for (int h = 0; h < 2; h++) {
            const int idx = t + h * 8192;
            const int k = idx >> 7, n = idx & 127;
            const int dst = ((k >> 3) * 128 + n) * 8 + (k & 7);
            W2b[dst] = (short)f2bf(W2[idx]);
            W3b[dst] = (short)f2bf(W3[idx]);
        }
    }
}

// ---------------------------------------------------------------------------
// Main fused kernel: grid=1024 (i = bid>>1, j0 = (bid&1)*256), block=512.
// LDS ~72 KB -> 2 blocks/CU. One barrier total.
// ---------------------------------------------------------------------------
__global__ __launch_bounds__(512, 4) void edge_main(
    const float* __restrict__ trans,
    const float* __restrict__ sctrans,
    const float* __restrict__ emask,
    const float* __restrict__ W1,
    const short* __restrict__ W2b,
    const float* __restrict__ b2,
    const short* __restrict__ W3b,
    const float* __restrict__ b3,
    const float* __restrict__ lng,
    const float* __restrict__ lnb,
    const float* __restrict__ A,
    const float* __restrict__ Bv,
    const float* __restrict__ Rm,
    float* __restrict__ out)
{
    __shared__ __align__(16) short hbuf[256 * 136];  // pitch 136 (+8 pad)
    __shared__ __align__(16) float As[128];
    __shared__ int binsD[256];
    __shared__ int binsS[256];

    const int tid = threadIdx.x;
    const int i  = blockIdx.x >> 1;
    const int j0 = (blockIdx.x & 1) << 8;

    if (tid < 128) As[tid] = A[i * 128 + tid];

    // ---- per-pair distogram bins (threads 0..255: trans, 256..511: sc_trans)
    {
        const int p = tid & 255;
        const float* P = (tid < 256) ? trans : sctrans;
        const int j = j0 + p;
        const float dx = __fsub_rn(P[i * 3 + 0], P[j * 3 + 0]);
        const float dy = __fsub_rn(P[i * 3 + 1], P[j * 3 + 1]);
        const float dz = __fsub_rn(P[i * 3 + 2], P[j * 3 + 2]);
        const float d2 = __fadd_rn(__fadd_rn(__fmul_rn(dx, dx), __fmul_rn(dy, dy)),
                                   __fmul_rn(dz, dz));
        const double dd = (double)sqrtf(d2);
        const double step = (20.0 - 0.001) / 21.0;
        int bin = -1;
        for (int b = 0; b < 22; b++) {
            const double lo = (b == 21) ? 20.0 : __dadd_rn(0.001, __dmul_rn((double)b, step));
            const double up = (b == 20) ? 20.0 :
                              ((b == 21) ? 1e8 : __dadd_rn(0.001, __dmul_rn((double)(b + 1), step)));
            if (dd > lo && dd < up) bin = b;
        }
        if (tid < 256) binsD[p] = bin; else binsS[p] = bin;
    }
    __syncthreads();   // the only barrier: bins + As visible to all

    const int w = tid >> 6;       // wave id: owns pairs [32w, 32w+32)
    const int l = tid & 63;
    const int q = l >> 4;         // quad within wave
    const int ln16 = l & 15;

    // ---- h1 assembly: pairs [32w,32w+32) x 128 feats (wave-private rows)
    for (int it = 0; it < 16; it++) {
        const int flat = it * 64 + l;          // 0..1023 = 32 pairs * 32 f4
        const int p = 32 * w + (flat >> 5);
        const int f = (flat & 31) << 2;
        const int j = j0 + p;
        const int didx = i - j + 511;
        const f32x4 bv = *(const f32x4*)&Bv[j * 128 + f];
        const f32x4 r  = *(const f32x4*)&Rm[didx * 128 + f];
        const f32x4 a  = *(const f32x4*)&As[f];
        const int bD = binsD[p], bS = binsS[p];
        const float sD = bD >= 0 ? 1.0f : 0.0f;
        const float sS = bS >= 0 ? 1.0f : 0.0f;
        const int rD = 384 + (bD >= 0 ? bD : 0);
        const int rS = 406 + (bS >= 0 ? bS : 0);
        const f32x4 wd  = *(const f32x4*)&W1[rD * 128 + f];
        const f32x4 wsv = *(const f32x4*)&W1[rS * 128 + f];
        float h0 = a.x + bv.x + r.x + sD * wd.x + sS * wsv.x;
        float h1 = a.y + bv.y + r.y + sD * wd.y + sS * wsv.y;
        float h2 = a.z + bv.z + r.z + sD * wd.z + sS * wsv.z;
        float h3 = a.w + bv.w + r.w + sD * wd.w + sS * wsv.w;
        h0 = fmaxf(h0, 0.0f); h1 = fmaxf(h1, 0.0f);
        h2 = fmaxf(h2, 0.0f); h3 = fmaxf(h3, 0.0f);
        uint2 pk;
        pk.x = cvt_pk_bf16(h0, h1);
        pk.y = cvt_pk_bf16(h2, h3);
        *(uint2*)&hbuf[p * 136 + f] = pk;
    }
    // no barrier: hbuf rows [32w,32w+32) only ever touched by wave w

    // ---- A-fragments for layer 2 (both 16-row M-tiles)
    bf16x8 af[2][4];
    for (int mt = 0; mt < 2; mt++)
        for (int kb = 0; kb < 4; kb++)
            af[mt][kb] = *(const bf16x8*)&hbuf[(32 * w + mt * 16 + ln16) * 136 + q * 8 + kb * 32];

    const f32x4 vzero = {0.0f, 0.0f, 0.0f, 0.0f};

    // ---- layer 2: per-nb accumulate + immediate writeback (8 VGPR acc)
    for (int nb = 0; nb < 8; nb++) {
        f32x4 a0 = vzero, a1 = vzero;
        for (int kb = 0; kb < 4; kb++) {
            const bf16x8 bfrg = *(const bf16x8*)&W2b[((kb * 4 + q) * 128 + nb * 16 + ln16) * 8];
            a0 = __builtin_amdgcn_mfma_f32_16x16x32_bf16(af[0][kb], bfrg, a0, 0, 0, 0);
            a1 = __builtin_amdgcn_mfma_f32_16x16x32_bf16(af[1][kb], bfrg, a1, 0, 0, 0);
        }
        const float b2v = b2[nb * 16 + ln16];
        for (int rg = 0; rg < 4; rg++) {
            const float v0 = fmaxf(a0[rg] + b2v, 0.0f);
            const float v1 = fmaxf(a1[rg] + b2v, 0.0f);
            hbuf[(32 * w +      q * 4 + rg) * 136 + nb * 16 + ln16] = (short)cvt_pk_bf16(v0, v0);
            hbuf[(32 * w + 16 + q * 4 + rg) * 136 + nb * 16 + ln16] = (short)cvt_pk_bf16(v1, v1);
        }
    }

    // ---- layer 3 + LayerNorm epilogue, per M-tile (32 VGPR acc)
    for (int mt = 0; mt < 2; mt++) {
        bf16x8 a3[4];
        for (int kb = 0; kb < 4; kb++)
            a3[kb] = *(const bf16x8*)&hbuf[(32 * w + mt * 16 + ln16) * 136 + q * 8 + kb * 32];

        f32x4 acc3[8];
        for (int nb = 0; nb < 8; nb++) acc3[nb] = vzero;
        for (int nb = 0; nb < 8; nb++)
            for (int kb = 0; kb < 4; kb++) {
                const bf16x8 bfrg = *(const bf16x8*)&W3b[((kb * 4 + q) * 128 + nb * 16 + ln16) * 8];
                acc3[nb] = __builtin_amdgcn_mfma_f32_16x16x32_bf16(a3[kb], bfrg, acc3[nb], 0, 0, 0);
            }

        float b3v[8], gv[8], bbv[8];
        for (int nb = 0; nb < 8; nb++) {
            const int n = nb * 16 + ln16;
            b3v[nb] = b3[n];
            gv[nb]  = lng[n];
            bbv[nb] = lnb[n];
        }
        for (int rg = 0; rg < 4; rg++) {
            float v[8];
            float s = 0.0f;
            for (int nb = 0; nb < 8; nb++) { v[nb] = acc3[nb][rg] + b3v[nb]; s += v[nb]; }
            for (int mm = 1; mm < 16; mm <<= 1) s += __shfl_xor(s, mm, 64);
            const float mu = s * (1.0f / 128.0f);
            float ss = 0.0f;
            for (int nb = 0; nb < 8; nb++) { const float dv = v[nb] - mu; ss += dv * dv; }
            for (int mm = 1; mm < 16; mm <<= 1) ss += __shfl_xor(ss, mm, 64);
            const float rstd = rsqrtf(ss * (1.0f / 128.0f) + 1e-5f);
            const int p = 32 * w + mt * 16 + q * 4 + rg;
            const int j = j0 + p;
            const float msk = emask[i * 512 + j];
            const int obase = (i * 512 + j) * 128;
            for (int nb = 0; nb < 8; nb++) {
                const float o = ((v[nb] - mu) * rstd * gv[nb] + bbv[nb]) * msk;
                out[obase + nb * 16 + ln16] = o;
            }
        }
    }
}

// ---------------------------------------------------------------------------
extern "C" void kernel_launch(void* const* d_in, const int* in_sizes, int n_in,
                              void* d_out, int out_size, void* d_ws, size_t ws_size,
                              hipStream_t stream)
{
    const float* nf    = (const float*)d_in[0];
    const float* trans = (const float*)d_in[1];
    const float* sctr  = (const float*)d_in[2];
    const float* emask = (const float*)d_in[3];
    const float* flow  = (const float*)d_in[4];
    const float* Wn2e  = (const float*)d_in[5];
    const float* bn2e  = (const float*)d_in[6];
    const float* Wrp   = (const float*)d_in[7];
    const float* brp   = (const float*)d_in[8];
    const float* W1    = (const float*)d_in[9];
    const float* b1    = (const float*)d_in[10];
    const float* W2    = (const float*)d_in[11];
    const float* b2    = (const float*)d_in[12];
    const float* W3    = (const float*)d_in[13];
    const float* b3    = (const float*)d_in[14];
    const float* lng   = (const float*)d_in[15];
    const float* lnb   = (const float*)d_in[16];

    float* ws = (float*)d_ws;                  // needs 278400 floats ~ 1.11 MB
    float* A   = ws;                           // [512*128]
    float* Bv  = ws + 512 * 128;               // [512*128]
    float* Rm  = ws + 2 * 512 * 128;           // [1023*128]
    short* W2b = (short*)(ws + 262016);        // [16384] bf16, frag layout
    short* W3b = (short*)(ws + 270208);        // [16384] bf16, frag layout
    float* out = (float*)d_out;

    pre_all<<<1599, 128, 0, stream>>>(nf, Wn2e, bn2e, W1, b1, flow, Wrp, brp,
                                      W2, W3, A, Bv, Rm, W2b, W3b);
    edge_main<<<1024, 512, 0, stream>>>(trans, sctr, emask, W1, W2b, b2, W3b, b3,
                                        lng, lnb, A, Bv, Rm, out);
}

// Round 2
// 258.967 us; speedup vs baseline: 1.0257x; 1.0257x over previous
//
#include <hip/hip_runtime.h>

// ---------------------------------------------------------------------------
// EdgeFeatureNet: B=1, N=512, NODE_DIM=256, HID=128, EDGE_DIM=128, bins=22
//
// h1_pre[i,j] = A[i] + Bv[j] + R[i-j+511] + W1row[384+binD] + W1row[406+binS]
// h2 = relu(h1@W2+b2), h3 = h2@W3+b3, LayerNorm, * edge_mask.
//
// Round-2 structure:
//  - W2/W3 pre-converted to bf16 fragment layout in pre_all (unchanged).
//  - edge_main stages them into LDS via global_load_lds width=16 (linear copy,
//    no VALU, no bank conflicts), hidden under the bins f64 loop.
//  - h1 computed DIRECTLY into MFMA A-fragment registers (no h1 LDS buffer).
//  - Only remaining LDS data buffer: wave-private 16x140 h2 tile (layer2->3
//    fragment remap), processed per 16-row M-tile. ONE barrier total.
//  - LDS ~104 KB -> 1 block/CU, 8 waves.
// ---------------------------------------------------------------------------

using bf16x8 = __attribute__((ext_vector_type(8))) short;
using f32x4  = __attribute__((ext_vector_type(4))) float;

__device__ __forceinline__ unsigned short f2bf(float f) {
    unsigned int u;
    __builtin_memcpy(&u, &f, 4);
    unsigned int r = (u + 0x7fffu + ((u >> 16) & 1u)) >> 16;  // RNE
    return (unsigned short)r;
}

__device__ __forceinline__ unsigned int cvt_pk_bf16(float lo, float hi) {
    unsigned int r;
    asm("v_cvt_pk_bf16_f32 %0, %1, %2" : "=v"(r) : "v"(lo), "v"(hi));
    return r;
}

// ---------------------------------------------------------------------------
// Merged pre-pass (unchanged from round 1):
//   blocks [0,512):     A[i], Bv[i] (b1/flow folded)
//   blocks [512,1535):  R[d] for d+511 in [0,1023)
//   blocks [1535,1599): W2/W3 f32 -> bf16 in MFMA fragment layout
// ---------------------------------------------------------------------------
__global__ void pre_all(const float* __restrict__ nf,
                        const float* __restrict__ Wn2e,
                        const float* __restrict__ bn2e,
                        const float* __restrict__ W1,
                        const float* __restrict__ b1,
                        const float* __restrict__ flow,
                        const float* __restrict__ Wrp,
                        const float* __restrict__ brp,
                        const float* __restrict__ W2,
                        const float* __restrict__ W3,
                        float* __restrict__ A, float* __restrict__ Bv,
                        float* __restrict__ Rm,
                        short* __restrict__ W2b, short* __restrict__ W3b)
{
    __shared__ float s0[256];
    __shared__ float s1[128];
    const int bid = blockIdx.x;
    const int m = threadIdx.x;

    if (bid < 512) {
        const int i = bid;
        s0[m]       = nf[i * 256 + m];
        s0[m + 128] = nf[i * 256 + 128 + m];
        __syncthreads();
        float acc = bn2e[m];
        for (int k = 0; k < 256; k++) acc += s0[k] * Wn2e[k * 128 + m];
        s1[m] = acc;
        __syncthreads();
        const float fl = flow[i];
        float aA = b1[m] + fl * W1[428 * 128 + m];
        float aB =         fl * W1[429 * 128 + m];
        for (int k = 0; k < 128; k++) {
            const float s = s1[k];
            aA += s * W1[k * 128 + m];
            aB += s * W1[(128 + k) * 128 + m];
        }
        A[i * 128 + m]  = aA;
        Bv[i * 128 + m] = aB;
    } else if (bid < 1535) {
        const int dix = bid - 512;
        const float d = (float)(dix - 511);
        const int K = m & 63;
        const float denom = powf(2056.0f, (float)K * (1.0f / 64.0f));
        const float ang = d * 3.14159265358979323846f / denom;
        s0[m] = (m < 64) ? sinf(ang) : cosf(ang);
        __syncthreads();
        float acc = brp[m];
        for (int k = 0; k < 128; k++) acc += s0[k] * Wrp[k * 128 + m];
        s1[m] = acc;
        __syncthreads();
        float acc2 = 0.0f;
        for (int k = 0; k < 128; k++) acc2 += s1[k] * W1[(256 + k) * 128 + m];
        Rm[dix * 128 + m] = acc2;
    } else {
        // fragment layout: dst = ((k>>3)*128 + n)*8 + (k&7), idx = k*128+n
        const int t = (bid - 1535) * 128 + m;           // 0..8191
        for (int h = 0; h < 2; h++) {
            const int idx = t + h * 8192;
            const int k = idx >> 7, n = idx & 127;
            const int dst = ((k >> 3) * 128 + n) * 8 + (k & 7);
            W2b[dst] = (short)f2bf(W2[idx]);
            W3b[dst] = (short)f2bf(W3[idx]);
        }
    }
}

// ---------------------------------------------------------------------------
// Main fused kernel: grid=1024 (i = bid>>1, j0 = (bid&1)*256), block=512.
// LDS ~104 KB -> 1 block/CU, 8 waves. One barrier.
// ---------------------------------------------------------------------------
__global__ __launch_bounds__(512, 2) void edge_main(
    const float* __restrict__ trans,
    const float* __restrict__ sctrans,
    const float* __restrict__ emask,
    const float* __restrict__ W1,
    const short* __restrict__ W2b,
    const float* __restrict__ b2,
    const short* __restrict__ W3b,
    const float* __restrict__ b3,
    const float* __restrict__ lng,
    const float* __restrict__ lnb,
    const float* __restrict__ A,
    const float* __restrict__ Bv,
    const float* __restrict__ Rm,
    float* __restrict__ out)
{
    __shared__ __align__(16) short W2L[16384];          // 32 KB, frag layout
    __shared__ __align__(16) short W3L[16384];          // 32 KB, frag layout
    __shared__ __align__(16) short h2w[8 * 16 * 140];   // 35 KB, wave-private
    __shared__ __align__(16) float As[128];
    __shared__ int binsD[256];
    __shared__ int binsS[256];

    const int tid = threadIdx.x;
    const int i  = blockIdx.x >> 1;
    const int j0 = (blockIdx.x & 1) << 8;

    // ---- async-stage weights into LDS: pure linear copy, 16 B/lane.
    // Dest = wave-uniform base + lane*16 (linear), as global_load_lds requires.
    for (int r = 0; r < 4; r++) {
        const int off = (r * 512 + tid) * 16;           // byte offset
        __builtin_amdgcn_global_load_lds(
            (const __attribute__((address_space(1))) void*)((const char*)W2b + off),
            (__attribute__((address_space(3))) void*)((char*)W2L + off), 16, 0, 0);
        __builtin_amdgcn_global_load_lds(
            (const __attribute__((address_space(1))) void*)((const char*)W3b + off),
            (__attribute__((address_space(3))) void*)((char*)W3L + off), 16, 0, 0);
    }

    if (tid < 128) As[tid] = A[i * 128 + tid];

    // ---- per-pair distogram bins (threads 0..255: trans, 256..511: sc_trans)
    {
        const int p = tid & 255;
        const float* P = (tid < 256) ? trans : sctrans;
        const int j = j0 + p;
        const float dx = __fsub_rn(P[i * 3 + 0], P[j * 3 + 0]);
        const float dy = __fsub_rn(P[i * 3 + 1], P[j * 3 + 1]);
        const float dz = __fsub_rn(P[i * 3 + 2], P[j * 3 + 2]);
        const float d2 = __fadd_rn(__fadd_rn(__fmul_rn(dx, dx), __fmul_rn(dy, dy)),
                                   __fmul_rn(dz, dz));
        const double dd = (double)sqrtf(d2);
        const double step = (20.0 - 0.001) / 21.0;
        int bin = -1;
        for (int b = 0; b < 22; b++) {
            const double lo = (b == 21) ? 20.0 : __dadd_rn(0.001, __dmul_rn((double)b, step));
            const double up = (b == 20) ? 20.0 :
                              ((b == 21) ? 1e8 : __dadd_rn(0.001, __dmul_rn((double)(b + 1), step)));
            if (dd > lo && dd < up) bin = b;
        }
        if (tid < 256) binsD[p] = bin; else binsS[p] = bin;
    }
    __syncthreads();   // only barrier: weights staged (vmcnt drained) + bins + As

    const int w = tid >> 6;       // wave id: owns pairs [32w, 32w+32)
    const int l = tid & 63;
    const int q = l >> 4;         // quad within wave
    const int ln16 = l & 15;

    // ---- h1 computed DIRECTLY into A-fragment registers.
    // Lane (q,ln16), tile mt, k-block kb holds h1[row=32w+mt*16+ln16][f0..f0+7],
    // f0 = kb*32 + q*8 — identical element mapping to the old hbuf load.
    bf16x8 af[2][4];
    for (int mt = 0; mt < 2; mt++) {
        const int p = 32 * w + mt * 16 + ln16;
        const int j = j0 + p;
        const int didx = i - j + 511;
        const int bD = binsD[p], bS = binsS[p];
        const float sD = bD >= 0 ? 1.0f : 0.0f;
        const float sS = bS >= 0 ? 1.0f : 0.0f;
        const int rD = 384 + (bD >= 0 ? bD : 0);
        const int rS = 406 + (bS >= 0 ? bS : 0);
        const float* __restrict__ BvR = &Bv[j * 128];
        const float* __restrict__ RmR = &Rm[didx * 128];
        const float* __restrict__ WdR = &W1[rD * 128];
        const float* __restrict__ WsR = &W1[rS * 128];
        for (int kb = 0; kb < 4; kb++) {
            const int f0 = kb * 32 + q * 8;
            const f32x4 bv0 = *(const f32x4*)&BvR[f0];
            const f32x4 bv1 = *(const f32x4*)&BvR[f0 + 4];
            const f32x4 r0  = *(const f32x4*)&RmR[f0];
            const f32x4 r1  = *(const f32x4*)&RmR[f0 + 4];
            const f32x4 a0  = *(const f32x4*)&As[f0];
            const f32x4 a1  = *(const f32x4*)&As[f0 + 4];
            const f32x4 w0  = *(const f32x4*)&WdR[f0];
            const f32x4 w1  = *(const f32x4*)&WdR[f0 + 4];
            const f32x4 s0  = *(const f32x4*)&WsR[f0];
            const f32x4 s1  = *(const f32x4*)&WsR[f0 + 4];
            float h[8];
            for (int e = 0; e < 4; e++) {
                h[e]     = fmaxf(a0[e] + bv0[e] + r0[e] + sD * w0[e] + sS * s0[e], 0.0f);
                h[e + 4] = fmaxf(a1[e] + bv1[e] + r1[e] + sD * w1[e] + sS * s1[e], 0.0f);
            }
            union { unsigned int u[4]; bf16x8 v; } cv;
            cv.u[0] = cvt_pk_bf16(h[0], h[1]);
            cv.u[1] = cvt_pk_bf16(h[2], h[3]);
            cv.u[2] = cvt_pk_bf16(h[4], h[5]);
            cv.u[3] = cvt_pk_bf16(h[6], h[7]);
            af[mt][kb] = cv.v;
        }
    }

    const f32x4 vzero = {0.0f, 0.0f, 0.0f, 0.0f};
    short* const h2p = &h2w[w * 16 * 140];   // wave-private 16x140 tile

    // per-lane epilogue constants (reused across both mt tiles)
    float b2v[8], b3v[8], gv[8], bbv[8];
    for (int nb = 0; nb < 8; nb++) {
        const int n = nb * 16 + ln16;
        b2v[nb] = b2[n]; b3v[nb] = b3[n]; gv[nb] = lng[n]; bbv[nb] = lnb[n];
    }

    for (int mt = 0; mt < 2; mt++) {
        // ---- layer 2: per-nb accumulate, relu+bias, write to wave-private LDS
        for (int nb = 0; nb < 8; nb++) {
            f32x4 acc = vzero;
            for (int kb = 0; kb < 4; kb++) {
                const bf16x8 bfrg = *(const bf16x8*)&W2L[((kb * 4 + q) * 128 + nb * 16 + ln16) * 8];
                acc = __builtin_amdgcn_mfma_f32_16x16x32_bf16(af[mt][kb], bfrg, acc, 0, 0, 0);
            }
            for (int rg = 0; rg < 4; rg++) {
                const float v = fmaxf(acc[rg] + b2v[nb], 0.0f);
                h2p[(q * 4 + rg) * 140 + nb * 16 + ln16] = (short)cvt_pk_bf16(v, v);
            }
        }

        // ---- layer 3 A-fragments from the wave-private tile (no barrier:
        // writes/reads are same-wave, ordered by lgkmcnt)
        bf16x8 a3[4];
        for (int kb = 0; kb < 4; kb++)
            a3[kb] = *(const bf16x8*)&h2p[ln16 * 140 + q * 8 + kb * 32];

        f32x4 acc3[8];
        for (int nb = 0; nb < 8; nb++) acc3[nb] = vzero;
        for (int nb = 0; nb < 8; nb++)
            for (int kb = 0; kb < 4; kb++) {
                const bf16x8 bfrg = *(const bf16x8*)&W3L[((kb * 4 + q) * 128 + nb * 16 + ln16) * 8];
                acc3[nb] = __builtin_amdgcn_mfma_f32_16x16x32_bf16(a3[kb], bfrg, acc3[nb], 0, 0, 0);
            }

        // ---- epilogue: +b3, LayerNorm over 128 (quad butterfly), *mask, store
        for (int rg = 0; rg < 4; rg++) {
            float v[8];
            float s = 0.0f;
            for (int nb = 0; nb < 8; nb++) { v[nb] = acc3[nb][rg] + b3v[nb]; s += v[nb]; }
            for (int mm = 1; mm < 16; mm <<= 1) s += __shfl_xor(s, mm, 64);
            const float mu = s * (1.0f / 128.0f);
            float ss = 0.0f;
            for (int nb = 0; nb < 8; nb++) { const float dv = v[nb] - mu; ss += dv * dv; }
            for (int mm = 1; mm < 16; mm <<= 1) ss += __shfl_xor(ss, mm, 64);
            const float rstd = rsqrtf(ss * (1.0f / 128.0f) + 1e-5f);
            const int p = 32 * w + mt * 16 + q * 4 + rg;
            const int j = j0 + p;
            const float msk = emask[i * 512 + j];
            const int obase = (i * 512 + j) * 128;
            for (int nb = 0; nb < 8; nb++) {
                const float o = ((v[nb] - mu) * rstd * gv[nb] + bbv[nb]) * msk;
                out[obase + nb * 16 + ln16] = o;
            }
        }
    }
}

// ---------------------------------------------------------------------------
extern "C" void kernel_launch(void* const* d_in, const int* in_sizes, int n_in,
                              void* d_out, int out_size, void* d_ws, size_t ws_size,
                              hipStream_t stream)
{
    const float* nf    = (const float*)d_in[0];
    const float* trans = (const float*)d_in[1];
    const float* sctr  = (const float*)d_in[2];
    const float* emask = (const float*)d_in[3];
    const float* flow  = (const float*)d_in[4];
    const float* Wn2e  = (const float*)d_in[5];
    const float* bn2e  = (const float*)d_in[6];
    const float* Wrp   = (const float*)d_in[7];
    const float* brp   = (const float*)d_in[8];
    const float* W1    = (const float*)d_in[9];
    const float* b1    = (const float*)d_in[10];
    const float* W2    = (const float*)d_in[11];
    const float* b2    = (const float*)d_in[12];
    const float* W3    = (const float*)d_in[13];
    const float* b3    = (const float*)d_in[14];
    const float* lng   = (const float*)d_in[15];
    const float* lnb   = (const float*)d_in[16];

    float* ws = (float*)d_ws;                  // needs ~1.11 MB
    float* A   = ws;                           // [512*128]
    float* Bv  = ws + 512 * 128;               // [512*128]
    float* Rm  = ws + 2 * 512 * 128;           // [1023*128]
    short* W2b = (short*)(ws + 262016);        // [16384] bf16, frag layout
    short* W3b = (short*)(ws + 270208);        // [16384] bf16, frag layout
    float* out = (float*)d_out;

    pre_all<<<1599, 128, 0, stream>>>(nf, Wn2e, bn2e, W1, b1, flow, Wrp, brp,
                                      W2, W3, A, Bv, Rm, W2b, W3b);
    edge_main<<<1024, 512, 0, stream>>>(trans, sctr, emask, W1, W2b, b2, W3b, b3,
                                        lng, lnb, A, Bv, Rm, out);
}

// Round 3
// 251.457 us; speedup vs baseline: 1.0563x; 1.0299x over previous
//
#include <hip/hip_runtime.h>

// ---------------------------------------------------------------------------
// EdgeFeatureNet: B=1, N=512, NODE_DIM=256, HID=128, EDGE_DIM=128, bins=22
//
// h1_pre[i,j] = A[i] + Bv[j] + R[i-j+511] + W1row[384+binD] + W1row[406+binS]
// h2 = relu(h1@W2+b2), h3 = h2@W3+b3, LayerNorm, * edge_mask.
//
// Round-3 structure:
//  - Layers 2/3 computed TRANSPOSED (h2T = W2T@h1T, h3T = W3T@h2T): the
//    pre-built weight fragments serve as A-operands unchanged, h1 A-frag is
//    h1T's B-frag. The L2->L3 remap is then a q-group lane permutation done
//    with 32 ds_bpermute per mt -> NO h2 LDS buffer at all.
//  - LDS 66.5 KB -> 2 blocks/CU (4 waves/SIMD), one barrier.
//  - Transposed C-layout gives each lane 4 consecutive cols: LayerNorm uses
//    2 shfl_xor (16/32), stores are dwordx4 (16 instrs vs 64).
//  - pre_all k-loops: multi-accumulator unroll -> 8-16 loads in flight.
// ---------------------------------------------------------------------------

using bf16x8 = __attribute__((ext_vector_type(8))) short;
using f32x4  = __attribute__((ext_vector_type(4))) float;

__device__ __forceinline__ unsigned short f2bf(float f) {
    unsigned int u;
    __builtin_memcpy(&u, &f, 4);
    unsigned int r = (u + 0x7fffu + ((u >> 16) & 1u)) >> 16;  // RNE
    return (unsigned short)r;
}

__device__ __forceinline__ unsigned int cvt_pk_bf16(float lo, float hi) {
    unsigned int r;
    asm("v_cvt_pk_bf16_f32 %0, %1, %2" : "=v"(r) : "v"(lo), "v"(hi));
    return r;
}

// ---------------------------------------------------------------------------
// Merged pre-pass:
//   blocks [0,512):     A[i], Bv[i] (b1/flow folded)
//   blocks [512,1535):  R[d] for d+511 in [0,1023)
//   blocks [1535,1599): W2/W3 f32 -> bf16 in MFMA fragment layout
// Inner k-loops use split accumulators so loads pipeline (latency fix).
// ---------------------------------------------------------------------------
__global__ void pre_all(const float* __restrict__ nf,
                        const float* __restrict__ Wn2e,
                        const float* __restrict__ bn2e,
                        const float* __restrict__ W1,
                        const float* __restrict__ b1,
                        const float* __restrict__ flow,
                        const float* __restrict__ Wrp,
                        const float* __restrict__ brp,
                        const float* __restrict__ W2,
                        const float* __restrict__ W3,
                        float* __restrict__ A, float* __restrict__ Bv,
                        float* __restrict__ Rm,
                        short* __restrict__ W2b, short* __restrict__ W3b)
{
    __shared__ float s0[256];
    __shared__ float s1[128];
    const int bid = blockIdx.x;
    const int m = threadIdx.x;

    if (bid < 512) {
        const int i = bid;
        s0[m]       = nf[i * 256 + m];
        s0[m + 128] = nf[i * 256 + 128 + m];
        __syncthreads();
        float c0 = 0.f, c1 = 0.f, c2 = 0.f, c3 = 0.f;
        #pragma unroll 4
        for (int k = 0; k < 256; k += 4) {
            c0 += s0[k + 0] * Wn2e[(k + 0) * 128 + m];
            c1 += s0[k + 1] * Wn2e[(k + 1) * 128 + m];
            c2 += s0[k + 2] * Wn2e[(k + 2) * 128 + m];
            c3 += s0[k + 3] * Wn2e[(k + 3) * 128 + m];
        }
        s1[m] = bn2e[m] + ((c0 + c1) + (c2 + c3));
        __syncthreads();
        const float fl = flow[i];
        float aA0 = b1[m] + fl * W1[428 * 128 + m], aA1 = 0.f;
        float aB0 =         fl * W1[429 * 128 + m], aB1 = 0.f;
        #pragma unroll 4
        for (int k = 0; k < 128; k += 2) {
            aA0 += s1[k]     * W1[(k) * 128 + m];
            aA1 += s1[k + 1] * W1[(k + 1) * 128 + m];
            aB0 += s1[k]     * W1[(128 + k) * 128 + m];
            aB1 += s1[k + 1] * W1[(129 + k) * 128 + m];
        }
        A[i * 128 + m]  = aA0 + aA1;
        Bv[i * 128 + m] = aB0 + aB1;
    } else if (bid < 1535) {
        const int dix = bid - 512;
        const float d = (float)(dix - 511);
        const int K = m & 63;
        const float denom = powf(2056.0f, (float)K * (1.0f / 64.0f));
        const float ang = d * 3.14159265358979323846f / denom;
        s0[m] = (m < 64) ? sinf(ang) : cosf(ang);
        __syncthreads();
        float c0 = 0.f, c1 = 0.f, c2 = 0.f, c3 = 0.f;
        #pragma unroll 4
        for (int k = 0; k < 128; k += 4) {
            c0 += s0[k + 0] * Wrp[(k + 0) * 128 + m];
            c1 += s0[k + 1] * Wrp[(k + 1) * 128 + m];
            c2 += s0[k + 2] * Wrp[(k + 2) * 128 + m];
            c3 += s0[k + 3] * Wrp[(k + 3) * 128 + m];
        }
        s1[m] = brp[m] + ((c0 + c1) + (c2 + c3));
        __syncthreads();
        c0 = 0.f; c1 = 0.f; c2 = 0.f; c3 = 0.f;
        #pragma unroll 4
        for (int k = 0; k < 128; k += 4) {
            c0 += s1[k + 0] * W1[(256 + k) * 128 + m];
            c1 += s1[k + 1] * W1[(257 + k) * 128 + m];
            c2 += s1[k + 2] * W1[(258 + k) * 128 + m];
            c3 += s1[k + 3] * W1[(259 + k) * 128 + m];
        }
        Rm[dix * 128 + m] = (c0 + c1) + (c2 + c3);
    } else {
        // fragment layout: dst = ((k>>3)*128 + n)*8 + (k&7), idx = k*128+n
        const int t = (bid - 1535) * 128 + m;           // 0..8191
        for (int h = 0; h < 2; h++) {
            const int idx = t + h * 8192;
            const int k = idx >> 7, n = idx & 127;
            const int dst = ((k >> 3) * 128 + n) * 8 + (k & 7);
            W2b[dst] = (short)f2bf(W2[idx]);
            W3b[dst] = (short)f2bf(W3[idx]);
        }
    }
}

// ---------------------------------------------------------------------------
// Main fused kernel: grid=1024 (i = bid>>1, j0 = (bid&1)*256), block=512.
// LDS ~66.5 KB -> 2 blocks/CU, 4 waves/SIMD. One barrier.
// ---------------------------------------------------------------------------
__global__ __launch_bounds__(512, 4) void edge_main(
    const float* __restrict__ trans,
    const float* __restrict__ sctrans,
    const float* __restrict__ emask,
    const float* __restrict__ W1,
    const short* __restrict__ W2b,
    const float* __restrict__ b2,
    const short* __restrict__ W3b,
    const float* __restrict__ b3,
    const float* __restrict__ lng,
    const float* __restrict__ lnb,
    const float* __restrict__ A,
    const float* __restrict__ Bv,
    const float* __restrict__ Rm,
    float* __restrict__ out)
{
    __shared__ __align__(16) short W2L[16384];          // 32 KB, frag layout
    __shared__ __align__(16) short W3L[16384];          // 32 KB, frag layout
    __shared__ __align__(16) float As[128];
    __shared__ int binsD[256];
    __shared__ int binsS[256];

    const int tid = threadIdx.x;
    const int i  = blockIdx.x >> 1;
    const int j0 = (blockIdx.x & 1) << 8;

    // ---- async-stage weights into LDS: pure linear copy, 16 B/lane.
    for (int r = 0; r < 4; r++) {
        const int off = (r * 512 + tid) * 16;           // byte offset
        __builtin_amdgcn_global_load_lds(
            (const __attribute__((address_space(1))) void*)((const char*)W2b + off),
            (__attribute__((address_space(3))) void*)((char*)W2L + off), 16, 0, 0);
        __builtin_amdgcn_global_load_lds(
            (const __attribute__((address_space(1))) void*)((const char*)W3b + off),
            (__attribute__((address_space(3))) void*)((char*)W3L + off), 16, 0, 0);
    }

    if (tid < 128) As[tid] = A[i * 128 + tid];

    // ---- per-pair distogram bins (threads 0..255: trans, 256..511: sc_trans)
    {
        const int p = tid & 255;
        const float* P = (tid < 256) ? trans : sctrans;
        const int j = j0 + p;
        const float dx = __fsub_rn(P[i * 3 + 0], P[j * 3 + 0]);
        const float dy = __fsub_rn(P[i * 3 + 1], P[j * 3 + 1]);
        const float dz = __fsub_rn(P[i * 3 + 2], P[j * 3 + 2]);
        const float d2 = __fadd_rn(__fadd_rn(__fmul_rn(dx, dx), __fmul_rn(dy, dy)),
                                   __fmul_rn(dz, dz));
        const double dd = (double)sqrtf(d2);
        const double step = (20.0 - 0.001) / 21.0;
        int bin = -1;
        for (int b = 0; b < 22; b++) {
            const double lo = (b == 21) ? 20.0 : __dadd_rn(0.001, __dmul_rn((double)b, step));
            const double up = (b == 20) ? 20.0 :
                              ((b == 21) ? 1e8 : __dadd_rn(0.001, __dmul_rn((double)(b + 1), step)));
            if (dd > lo && dd < up) bin = b;
        }
        if (tid < 256) binsD[p] = bin; else binsS[p] = bin;
    }
    __syncthreads();   // only barrier: weights staged + bins + As

    const int w = tid >> 6;       // wave id: owns pairs [32w, 32w+32)
    const int l = tid & 63;
    const int q = l >> 4;         // quad within wave
    const int ln16 = l & 15;

    const f32x4 vzero = {0.0f, 0.0f, 0.0f, 0.0f};
    // bpermute source-lane addresses for the L2->L3 q-group permutation
    const int laA = (((q & 1) * 2) * 16 + ln16) * 4;    // source quad (q&1)*2
    const int laB = laA + 64;                            // source quad (q&1)*2+1
    const bool selHi = (q >> 1) != 0;

    for (int mt = 0; mt < 2; mt++) {
        const int p = 32 * w + mt * 16 + ln16;          // local pair (row r)
        const int j = j0 + p;

        // ---- h1 directly into A-frag registers (== B-frag of h1T).
        // Lane (q,ln16), kb holds h1[row=p][f = kb*32 + q*8 + e], e=0..7.
        bf16x8 af[4];
        {
            const int didx = i - j + 511;
            const int bD = binsD[p], bS = binsS[p];
            const float sD = bD >= 0 ? 1.0f : 0.0f;
            const float sS = bS >= 0 ? 1.0f : 0.0f;
            const int rD = 384 + (bD >= 0 ? bD : 0);
            const int rS = 406 + (bS >= 0 ? bS : 0);
            const float* __restrict__ BvR = &Bv[j * 128];
            const float* __restrict__ RmR = &Rm[didx * 128];
            const float* __restrict__ WdR = &W1[rD * 128];
            const float* __restrict__ WsR = &W1[rS * 128];
            #pragma unroll
            for (int kb = 0; kb < 4; kb++) {
                const int f0 = kb * 32 + q * 8;
                const f32x4 bv0 = *(const f32x4*)&BvR[f0];
                const f32x4 bv1 = *(const f32x4*)&BvR[f0 + 4];
                const f32x4 r0  = *(const f32x4*)&RmR[f0];
                const f32x4 r1  = *(const f32x4*)&RmR[f0 + 4];
                const f32x4 a0  = *(const f32x4*)&As[f0];
                const f32x4 a1  = *(const f32x4*)&As[f0 + 4];
                const f32x4 w0  = *(const f32x4*)&WdR[f0];
                const f32x4 w1  = *(const f32x4*)&WdR[f0 + 4];
                const f32x4 s0  = *(const f32x4*)&WsR[f0];
                const f32x4 s1  = *(const f32x4*)&WsR[f0 + 4];
                float h[8];
                #pragma unroll
                for (int e = 0; e < 4; e++) {
                    h[e]     = fmaxf(a0[e] + bv0[e] + r0[e] + sD * w0[e] + sS * s0[e], 0.0f);
                    h[e + 4] = fmaxf(a1[e] + bv1[e] + r1[e] + sD * w1[e] + sS * s1[e], 0.0f);
                }
                union { unsigned int u[4]; bf16x8 v; } cv;
                cv.u[0] = cvt_pk_bf16(h[0], h[1]);
                cv.u[1] = cvt_pk_bf16(h[2], h[3]);
                cv.u[2] = cvt_pk_bf16(h[4], h[5]);
                cv.u[3] = cvt_pk_bf16(h[6], h[7]);
                af[kb] = cv.v;
            }
        }

        // ---- layer 2 TRANSPOSED: h2T[nt-tile] = sum_kb W2T-frag x h1T-frag.
        // C-layout: lane holds h2T[n = nt*16+q*4+rg][r = ln16] = h2[r][n].
        // Pack relu(.+b2) pairs as bf16: P[nt][0]=(rg0,rg1), P[nt][1]=(rg2,rg3).
        unsigned int P[8][2];
        #pragma unroll
        for (int nt = 0; nt < 8; nt++) {
            f32x4 acc2 = vzero;
            #pragma unroll
            for (int kb = 0; kb < 4; kb++) {
                const bf16x8 wf = *(const bf16x8*)&W2L[((kb * 4 + q) * 128 + nt * 16 + ln16) * 8];
                acc2 = __builtin_amdgcn_mfma_f32_16x16x32_bf16(wf, af[kb], acc2, 0, 0, 0);
            }
            const f32x4 b2c = *(const f32x4*)&b2[nt * 16 + q * 4];
            P[nt][0] = cvt_pk_bf16(fmaxf(acc2[0] + b2c[0], 0.0f),
                                   fmaxf(acc2[1] + b2c[1], 0.0f));
            P[nt][1] = cvt_pk_bf16(fmaxf(acc2[2] + b2c[2], 0.0f),
                                   fmaxf(acc2[3] + b2c[3], 0.0f));
        }

        // ---- layer 3 TRANSPOSED. B-frag of h2T built from P via q-group
        // permutation: dest (q,ln16) u32[p'] = P[2kb + (q>>1)][p'&1] of lane
        // ((q&1)*2 + (p'>>1))*16 + ln16 — whole-u32 moves, 8 bpermute/kb.
        f32x4 acc3[8];
        #pragma unroll
        for (int nt = 0; nt < 8; nt++) acc3[nt] = vzero;
        #pragma unroll
        for (int kb = 0; kb < 4; kb++) {
            const int r0a = __builtin_amdgcn_ds_bpermute(laA, (int)P[2 * kb][0]);
            const int r1a = __builtin_amdgcn_ds_bpermute(laA, (int)P[2 * kb][1]);
            const int r2a = __builtin_amdgcn_ds_bpermute(laB, (int)P[2 * kb][0]);
            const int r3a = __builtin_amdgcn_ds_bpermute(laB, (int)P[2 * kb][1]);
            const int r0b = __builtin_amdgcn_ds_bpermute(laA, (int)P[2 * kb + 1][0]);
            const int r1b = __builtin_amdgcn_ds_bpermute(laA, (int)P[2 * kb + 1][1]);
            const int r2b = __builtin_amdgcn_ds_bpermute(laB, (int)P[2 * kb + 1][0]);
            const int r3b = __builtin_amdgcn_ds_bpermute(laB, (int)P[2 * kb + 1][1]);
            union { unsigned int u[4]; bf16x8 v; } bf;
            bf.u[0] = (unsigned int)(selHi ? r0b : r0a);
            bf.u[1] = (unsigned int)(selHi ? r1b : r1a);
            bf.u[2] = (unsigned int)(selHi ? r2b : r2a);
            bf.u[3] = (unsigned int)(selHi ? r3b : r3a);
            #pragma unroll
            for (int nt = 0; nt < 8; nt++) {
                const bf16x8 wf = *(const bf16x8*)&W3L[((kb * 4 + q) * 128 + nt * 16 + ln16) * 8];
                acc3[nt] = __builtin_amdgcn_mfma_f32_16x16x32_bf16(wf, bf.v, acc3[nt], 0, 0, 0);
            }
        }

        // ---- epilogue. Lane holds h3[r=ln16][n = nt*16+q*4+rg] (32 vals).
        // LayerNorm over n: lane-local sum + 2 shfl_xor across the 4 q-lanes.
        float s = 0.0f;
        #pragma unroll
        for (int nt = 0; nt < 8; nt++) {
            const f32x4 b3c = *(const f32x4*)&b3[nt * 16 + q * 4];
            #pragma unroll
            for (int rg = 0; rg < 4; rg++) {
                acc3[nt][rg] += b3c[rg];
                s += acc3[nt][rg];
            }
        }
        s += __shfl_xor(s, 16, 64);
        s += __shfl_xor(s, 32, 64);
        const float mu = s * (1.0f / 128.0f);
        float ss = 0.0f;
        #pragma unroll
        for (int nt = 0; nt < 8; nt++)
            #pragma unroll
            for (int rg = 0; rg < 4; rg++) {
                const float dv = acc3[nt][rg] - mu;
                ss += dv * dv;
            }
        ss += __shfl_xor(ss, 16, 64);
        ss += __shfl_xor(ss, 32, 64);
        const float rstd = rsqrtf(ss * (1.0f / 128.0f) + 1e-5f);
        const float msk = emask[i * 512 + j];
        float* __restrict__ orow = &out[(i * 512 + j) * 128];
        #pragma unroll
        for (int nt = 0; nt < 8; nt++) {
            const f32x4 gc = *(const f32x4*)&lng[nt * 16 + q * 4];
            const f32x4 bc = *(const f32x4*)&lnb[nt * 16 + q * 4];
            f32x4 o;
            #pragma unroll
            for (int rg = 0; rg < 4; rg++)
                o[rg] = ((acc3[nt][rg] - mu) * rstd * gc[rg] + bc[rg]) * msk;
            *(f32x4*)&orow[nt * 16 + q * 4] = o;
        }
    }
}

// ---------------------------------------------------------------------------
extern "C" void kernel_launch(void* const* d_in, const int* in_sizes, int n_in,
                              void* d_out, int out_size, void* d_ws, size_t ws_size,
                              hipStream_t stream)
{
    const float* nf    = (const float*)d_in[0];
    const float* trans = (const float*)d_in[1];
    const float* sctr  = (const float*)d_in[2];
    const float* emask = (const float*)d_in[3];
    const float* flow  = (const float*)d_in[4];
    const float* Wn2e  = (const float*)d_in[5];
    const float* bn2e  = (const float*)d_in[6];
    const float* Wrp   = (const float*)d_in[7];
    const float* brp   = (const float*)d_in[8];
    const float* W1    = (const float*)d_in[9];
    const float* b1    = (const float*)d_in[10];
    const float* W2    = (const float*)d_in[11];
    const float* b2    = (const float*)d_in[12];
    const float* W3    = (const float*)d_in[13];
    const float* b3    = (const float*)d_in[14];
    const float* lng   = (const float*)d_in[15];
    const float* lnb   = (const float*)d_in[16];

    float* ws = (float*)d_ws;                  // needs ~1.11 MB
    float* A   = ws;                           // [512*128]
    float* Bv  = ws + 512 * 128;               // [512*128]
    float* Rm  = ws + 2 * 512 * 128;           // [1023*128]
    short* W2b = (short*)(ws + 262016);        // [16384] bf16, frag layout
    short* W3b = (short*)(ws + 270208);        // [16384] bf16, frag layout
    float* out = (float*)d_out;

    pre_all<<<1599, 128, 0, stream>>>(nf, Wn2e, bn2e, W1, b1, flow, Wrp, brp,
                                      W2, W3, A, Bv, Rm, W2b, W3b);
    edge_main<<<1024, 512, 0, stream>>>(trans, sctr, emask, W1, W2b, b2, W3b, b3,
                                        lng, lnb, A, Bv, Rm, out);
}

// Round 5
// 249.946 us; speedup vs baseline: 1.0627x; 1.0060x over previous
//
#include <hip/hip_runtime.h>

// ---------------------------------------------------------------------------
// EdgeFeatureNet: B=1, N=512, NODE_DIM=256, HID=128, EDGE_DIM=128, bins=22
//
// h1_pre[i,j] = A[i] + Bv[j] + R[i-j+511] + W1row[384+binD] + W1row[406+binS]
// h2 = relu(h1@W2+b2), h3 = h2@W3+b3, LayerNorm, * edge_mask.
//
// Round-5 structure (cooperative launch abandoned — deadlock risk):
//  - pre_fast: 512 blocks x 512 threads. Block i computes A[i], Bv[i]
//    (k-sliced 4-way + LDS reduce), two Rm rows, and a 64-elem slice of the
//    W2/W3 bf16 fragment conversion. Replaces the latency-bound 128-thread
//    pre_all (rolled 256-iter dependent chains).
//  - edge_main: ROUND-3 KERNEL VERBATIM (verified, 99.9 us): transposed
//    MFMA layers 2/3, q-group bpermute remap, no h2 LDS, 2 blocks/CU,
//    one barrier.
// ---------------------------------------------------------------------------

using bf16x8 = __attribute__((ext_vector_type(8))) short;
using f32x4  = __attribute__((ext_vector_type(4))) float;

__device__ __forceinline__ unsigned short f2bf(float f) {
    unsigned int u;
    __builtin_memcpy(&u, &f, 4);
    unsigned int r = (u + 0x7fffu + ((u >> 16) & 1u)) >> 16;  // RNE
    return (unsigned short)r;
}

__device__ __forceinline__ unsigned int cvt_pk_bf16(float lo, float hi) {
    unsigned int r;
    asm("v_cvt_pk_bf16_f32 %0, %1, %2" : "=v"(r) : "v"(lo), "v"(hi));
    return r;
}

// ---------------------------------------------------------------------------
// pre_fast: 512 blocks x 512 threads.
//   block i: A[i], Bv[i]; Rm rows {2i, 2i+1}; 64-elem W2b/W3b slice.
// All matvecs k-sliced: thread (ks=tid>>7, m=tid&127) accumulates a quarter
// of k, partials reduced via LDS. ~256 MACs/thread, loads pipelined.
// ---------------------------------------------------------------------------
__global__ __launch_bounds__(512) void pre_fast(
    const float* __restrict__ nf,
    const float* __restrict__ flow,
    const float* __restrict__ Wn2e,
    const float* __restrict__ bn2e,
    const float* __restrict__ Wrp,
    const float* __restrict__ brp,
    const float* __restrict__ W1,
    const float* __restrict__ b1,
    const float* __restrict__ W2,
    const float* __restrict__ W3,
    float* __restrict__ Aw, float* __restrict__ Bv,
    float* __restrict__ Rm,
    short* __restrict__ W2b, short* __restrict__ W3b)
{
    __shared__ float nfs[256];
    __shared__ float n2s[128];
    __shared__ float red[512];
    __shared__ float emb[128];
    __shared__ float rp[128];

    const int bid = blockIdx.x;
    const int tid = threadIdx.x;
    const int i = bid;
    const int m = tid & 127, ks = tid >> 7;

    // (c) W2/W3 -> bf16 fragment layout, 64 values per block (independent)
    if (tid < 64) {
        const int idx = bid * 64 + tid;            // 0..32767
        const int v   = idx & 16383;
        const int k   = v >> 7, n = v & 127;
        const int dst = ((k >> 3) * 128 + n) * 8 + (k & 7);
        if (idx < 16384) W2b[dst] = (short)f2bf(W2[v]);
        else             W3b[dst] = (short)f2bf(W3[v]);
    }

    // (a) n2e[i] = nf[i] @ Wn2e + bn2e   (k = 0..255, 4 slices of 64)
    if (tid < 256) nfs[tid] = nf[i * 256 + tid];
    __syncthreads();
    {
        float p0 = 0.f, p1 = 0.f;
        #pragma unroll 8
        for (int k = ks * 64; k < ks * 64 + 64; k += 2) {
            p0 += nfs[k]     * Wn2e[k * 128 + m];
            p1 += nfs[k + 1] * Wn2e[(k + 1) * 128 + m];
        }
        red[tid] = p0 + p1;
    }
    __syncthreads();
    if (tid < 128)
        n2s[tid] = bn2e[tid] +
                   ((red[tid] + red[tid + 128]) + (red[tid + 256] + red[tid + 384]));
    __syncthreads();

    // A[i] = n2e@W1[0:128] + b1 + flow*W1[428];  Bv[i] = n2e@W1[128:256] + flow*W1[429]
    {
        float pa = 0.f, pb = 0.f;
        #pragma unroll 8
        for (int k = ks * 32; k < ks * 32 + 32; k++) {
            const float s = n2s[k];
            pa += s * W1[k * 128 + m];
            pb += s * W1[(128 + k) * 128 + m];
        }
        red[tid] = pa;
        __syncthreads();
        float pA = 0.f;
        if (tid < 128)
            pA = (red[tid] + red[tid + 128]) + (red[tid + 256] + red[tid + 384]);
        __syncthreads();
        red[tid] = pb;
        __syncthreads();
        if (tid < 128) {
            const float fl = flow[i];
            Aw[i * 128 + tid] = pA + b1[tid] + fl * W1[428 * 128 + tid];
            Bv[i * 128 + tid] =
                (red[tid] + red[tid + 128]) + (red[tid + 256] + red[tid + 384]) +
                fl * W1[429 * 128 + tid];
        }
    }
    __syncthreads();

    // (b) two Rm rows: dix = 2*bid, 2*bid+1 (valid 0..1022)
    for (int rr = 0; rr < 2; rr++) {
        const int dix = bid * 2 + rr;
        if (dix > 1022) break;                      // block-uniform
        const float d = (float)(dix - 511);
        if (tid < 128) {
            const int K = tid & 63;
            const float denom = powf(2056.0f, (float)K * (1.0f / 64.0f));
            const float ang = d * 3.14159265358979323846f / denom;
            emb[tid] = (tid < 64) ? sinf(ang) : cosf(ang);
        }
        __syncthreads();
        float p = 0.f;
        #pragma unroll 8
        for (int k = ks * 32; k < ks * 32 + 32; k++) p += emb[k] * Wrp[k * 128 + m];
        red[tid] = p;
        __syncthreads();
        if (tid < 128)
            rp[tid] = brp[tid] +
                      ((red[tid] + red[tid + 128]) + (red[tid + 256] + red[tid + 384]));
        __syncthreads();
        p = 0.f;
        #pragma unroll 8
        for (int k = ks * 32; k < ks * 32 + 32; k++) p += rp[k] * W1[(256 + k) * 128 + m];
        red[tid] = p;
        __syncthreads();
        if (tid < 128)
            Rm[dix * 128 + tid] =
                (red[tid] + red[tid + 128]) + (red[tid + 256] + red[tid + 384]);
        __syncthreads();
    }
}

// ---------------------------------------------------------------------------
// Main fused kernel — ROUND-3 VERBATIM (verified): grid=1024 (i = bid>>1,
// j0 = (bid&1)*256), block=512. LDS ~66.5 KB -> 2 blocks/CU. One barrier.
// ---------------------------------------------------------------------------
__global__ __launch_bounds__(512, 4) void edge_main(
    const float* __restrict__ trans,
    const float* __restrict__ sctrans,
    const float* __restrict__ emask,
    const float* __restrict__ W1,
    const short* __restrict__ W2b,
    const float* __restrict__ b2,
    const short* __restrict__ W3b,
    const float* __restrict__ b3,
    const float* __restrict__ lng,
    const float* __restrict__ lnb,
    const float* __restrict__ A,
    const float* __restrict__ Bv,
    const float* __restrict__ Rm,
    float* __restrict__ out)
{
    __shared__ __align__(16) short W2L[16384];          // 32 KB, frag layout
    __shared__ __align__(16) short W3L[16384];          // 32 KB, frag layout
    __shared__ __align__(16) float As[128];
    __shared__ int binsD[256];
    __shared__ int binsS[256];

    const int tid = threadIdx.x;
    const int i  = blockIdx.x >> 1;
    const int j0 = (blockIdx.x & 1) << 8;

    // ---- async-stage weights into LDS: pure linear copy, 16 B/lane.
    for (int r = 0; r < 4; r++) {
        const int off = (r * 512 + tid) * 16;           // byte offset
        __builtin_amdgcn_global_load_lds(
            (const __attribute__((address_space(1))) void*)((const char*)W2b + off),
            (__attribute__((address_space(3))) void*)((char*)W2L + off), 16, 0, 0);
        __builtin_amdgcn_global_load_lds(
            (const __attribute__((address_space(1))) void*)((const char*)W3b + off),
            (__attribute__((address_space(3))) void*)((char*)W3L + off), 16, 0, 0);
    }

    if (tid < 128) As[tid] = A[i * 128 + tid];

    // ---- per-pair distogram bins (threads 0..255: trans, 256..511: sc_trans)
    {
        const int p = tid & 255;
        const float* P = (tid < 256) ? trans : sctrans;
        const int j = j0 + p;
        const float dx = __fsub_rn(P[i * 3 + 0], P[j * 3 + 0]);
        const float dy = __fsub_rn(P[i * 3 + 1], P[j * 3 + 1]);
        const float dz = __fsub_rn(P[i * 3 + 2], P[j * 3 + 2]);
        const float d2 = __fadd_rn(__fadd_rn(__fmul_rn(dx, dx), __fmul_rn(dy, dy)),
                                   __fmul_rn(dz, dz));
        const double dd = (double)sqrtf(d2);
        const double step = (20.0 - 0.001) / 21.0;
        int bin = -1;
        for (int b = 0; b < 22; b++) {
            const double lo = (b == 21) ? 20.0 : __dadd_rn(0.001, __dmul_rn((double)b, step));
            const double up = (b == 20) ? 20.0 :
                              ((b == 21) ? 1e8 : __dadd_rn(0.001, __dmul_rn((double)(b + 1), step)));
            if (dd > lo && dd < up) bin = b;
        }
        if (tid < 256) binsD[p] = bin; else binsS[p] = bin;
    }
    __syncthreads();   // only barrier: weights staged + bins + As

    const int w = tid >> 6;       // wave id: owns pairs [32w, 32w+32)
    const int l = tid & 63;
    const int q = l >> 4;         // quad within wave
    const int ln16 = l & 15;

    const f32x4 vzero = {0.0f, 0.0f, 0.0f, 0.0f};
    // bpermute source-lane addresses for the L2->L3 q-group permutation
    const int laA = (((q & 1) * 2) * 16 + ln16) * 4;    // source quad (q&1)*2
    const int laB = laA + 64;                            // source quad (q&1)*2+1
    const bool selHi = (q >> 1) != 0;

    for (int mt = 0; mt < 2; mt++) {
        const int p = 32 * w + mt * 16 + ln16;          // local pair (row r)
        const int j = j0 + p;

        // ---- h1 directly into A-frag registers (== B-frag of h1T).
        // Lane (q,ln16), kb holds h1[row=p][f = kb*32 + q*8 + e], e=0..7.
        bf16x8 af[4];
        {
            const int didx = i - j + 511;
            const int bD = binsD[p], bS = binsS[p];
            const float sD = bD >= 0 ? 1.0f : 0.0f;
            const float sS = bS >= 0 ? 1.0f : 0.0f;
            const int rD = 384 + (bD >= 0 ? bD : 0);
            const int rS = 406 + (bS >= 0 ? bS : 0);
            const float* __restrict__ BvR = &Bv[j * 128];
            const float* __restrict__ RmR = &Rm[didx * 128];
            const float* __restrict__ WdR = &W1[rD * 128];
            const float* __restrict__ WsR = &W1[rS * 128];
            #pragma unroll
            for (int kb = 0; kb < 4; kb++) {
                const int f0 = kb * 32 + q * 8;
                const f32x4 bv0 = *(const f32x4*)&BvR[f0];
                const f32x4 bv1 = *(const f32x4*)&BvR[f0 + 4];
                const f32x4 r0  = *(const f32x4*)&RmR[f0];
                const f32x4 r1  = *(const f32x4*)&RmR[f0 + 4];
                const f32x4 a0  = *(const f32x4*)&As[f0];
                const f32x4 a1  = *(const f32x4*)&As[f0 + 4];
                const f32x4 w0  = *(const f32x4*)&WdR[f0];
                const f32x4 w1  = *(const f32x4*)&WdR[f0 + 4];
                const f32x4 s0  = *(const f32x4*)&WsR[f0];
                const f32x4 s1  = *(const f32x4*)&WsR[f0 + 4];
                float h[8];
                #pragma unroll
                for (int e = 0; e < 4; e++) {
                    h[e]     = fmaxf(a0[e] + bv0[e] + r0[e] + sD * w0[e] + sS * s0[e], 0.0f);
                    h[e + 4] = fmaxf(a1[e] + bv1[e] + r1[e] + sD * w1[e] + sS * s1[e], 0.0f);
                }
                union { unsigned int u[4]; bf16x8 v; } cv;
                cv.u[0] = cvt_pk_bf16(h[0], h[1]);
                cv.u[1] = cvt_pk_bf16(h[2], h[3]);
                cv.u[2] = cvt_pk_bf16(h[4], h[5]);
                cv.u[3] = cvt_pk_bf16(h[6], h[7]);
                af[kb] = cv.v;
            }
        }

        // ---- layer 2 TRANSPOSED: h2T[nt-tile] = sum_kb W2T-frag x h1T-frag.
        unsigned int P[8][2];
        #pragma unroll
        for (int nt = 0; nt < 8; nt++) {
            f32x4 acc2 = vzero;
            #pragma unroll
            for (int kb = 0; kb < 4; kb++) {
                const bf16x8 wf = *(const bf16x8*)&W2L[((kb * 4 + q) * 128 + nt * 16 + ln16) * 8];
                acc2 = __builtin_amdgcn_mfma_f32_16x16x32_bf16(wf, af[kb], acc2, 0, 0, 0);
            }
            const f32x4 b2c = *(const f32x4*)&b2[nt * 16 + q * 4];
            P[nt][0] = cvt_pk_bf16(fmaxf(acc2[0] + b2c[0], 0.0f),
                                   fmaxf(acc2[1] + b2c[1], 0.0f));
            P[nt][1] = cvt_pk_bf16(fmaxf(acc2[2] + b2c[2], 0.0f),
                                   fmaxf(acc2[3] + b2c[3], 0.0f));
        }

        // ---- layer 3 TRANSPOSED: B-frag via q-group lane permutation
        f32x4 acc3[8];
        #pragma unroll
        for (int nt = 0; nt < 8; nt++) acc3[nt] = vzero;
        #pragma unroll
        for (int kb = 0; kb < 4; kb++) {
            const int r0a = __builtin_amdgcn_ds_bpermute(laA, (int)P[2 * kb][0]);
            const int r1a = __builtin_amdgcn_ds_bpermute(laA, (int)P[2 * kb][1]);
            const int r2a = __builtin_amdgcn_ds_bpermute(laB, (int)P[2 * kb][0]);
            const int r3a = __builtin_amdgcn_ds_bpermute(laB, (int)P[2 * kb][1]);
            const int r0b = __builtin_amdgcn_ds_bpermute(laA, (int)P[2 * kb + 1][0]);
            const int r1b = __builtin_amdgcn_ds_bpermute(laA, (int)P[2 * kb + 1][1]);
            const int r2b = __builtin_amdgcn_ds_bpermute(laB, (int)P[2 * kb + 1][0]);
            const int r3b = __builtin_amdgcn_ds_bpermute(laB, (int)P[2 * kb + 1][1]);
            union { unsigned int u[4]; bf16x8 v; } bf;
            bf.u[0] = (unsigned int)(selHi ? r0b : r0a);
            bf.u[1] = (unsigned int)(selHi ? r1b : r1a);
            bf.u[2] = (unsigned int)(selHi ? r2b : r2a);
            bf.u[3] = (unsigned int)(selHi ? r3b : r3a);
            #pragma unroll
            for (int nt = 0; nt < 8; nt++) {
                const bf16x8 wf = *(const bf16x8*)&W3L[((kb * 4 + q) * 128 + nt * 16 + ln16) * 8];
                acc3[nt] = __builtin_amdgcn_mfma_f32_16x16x32_bf16(wf, bf.v, acc3[nt], 0, 0, 0);
            }
        }

        // ---- epilogue. Lane holds h3[r=ln16][n = nt*16+q*4+rg] (32 vals).
        float s = 0.0f;
        #pragma unroll
        for (int nt = 0; nt < 8; nt++) {
            const f32x4 b3c = *(const f32x4*)&b3[nt * 16 + q * 4];
            #pragma unroll
            for (int rg = 0; rg < 4; rg++) {
                acc3[nt][rg] += b3c[rg];
                s += acc3[nt][rg];
            }
        }
        s += __shfl_xor(s, 16, 64);
        s += __shfl_xor(s, 32, 64);
        const float mu = s * (1.0f / 128.0f);
        float ss = 0.0f;
        #pragma unroll
        for (int nt = 0; nt < 8; nt++)
            #pragma unroll
            for (int rg = 0; rg < 4; rg++) {
                const float dv = acc3[nt][rg] - mu;
                ss += dv * dv;
            }
        ss += __shfl_xor(ss, 16, 64);
        ss += __shfl_xor(ss, 32, 64);
        const float rstd = rsqrtf(ss * (1.0f / 128.0f) + 1e-5f);
        const float msk = emask[i * 512 + j];
        float* __restrict__ orow = &out[(i * 512 + j) * 128];
        #pragma unroll
        for (int nt = 0; nt < 8; nt++) {
            const f32x4 gc = *(const f32x4*)&lng[nt * 16 + q * 4];
            const f32x4 bc = *(const f32x4*)&lnb[nt * 16 + q * 4];
            f32x4 o;
            #pragma unroll
            for (int rg = 0; rg < 4; rg++)
                o[rg] = ((acc3[nt][rg] - mu) * rstd * gc[rg] + bc[rg]) * msk;
            *(f32x4*)&orow[nt * 16 + q * 4] = o;
        }
    }
}

// ---------------------------------------------------------------------------
extern "C" void kernel_launch(void* const* d_in, const int* in_sizes, int n_in,
                              void* d_out, int out_size, void* d_ws, size_t ws_size,
                              hipStream_t stream)
{
    const float* nf    = (const float*)d_in[0];
    const float* trans = (const float*)d_in[1];
    const float* sctr  = (const float*)d_in[2];
    const float* emask = (const float*)d_in[3];
    const float* flow  = (const float*)d_in[4];
    const float* Wn2e  = (const float*)d_in[5];
    const float* bn2e  = (const float*)d_in[6];
    const float* Wrp   = (const float*)d_in[7];
    const float* brp   = (const float*)d_in[8];
    const float* W1    = (const float*)d_in[9];
    const float* b1    = (const float*)d_in[10];
    const float* W2    = (const float*)d_in[11];
    const float* b2    = (const float*)d_in[12];
    const float* W3    = (const float*)d_in[13];
    const float* b3    = (const float*)d_in[14];
    const float* lng   = (const float*)d_in[15];
    const float* lnb   = (const float*)d_in[16];

    float* ws = (float*)d_ws;                  // needs ~1.07 MB
    float* Aw  = ws;                           // [512*128]
    float* Bv  = ws + 65536;                   // [512*128]
    float* Rm  = ws + 131072;                  // [1023*128]
    short* W2b = (short*)(ws + 262016);        // [16384] bf16, frag layout
    short* W3b = (short*)(ws + 270208);        // [16384] bf16, frag layout
    float* out = (float*)d_out;

    pre_fast<<<512, 512, 0, stream>>>(nf, flow, Wn2e, bn2e, Wrp, brp, W1, b1,
                                      W2, W3, Aw, Bv, Rm, W2b, W3b);
    edge_main<<<1024, 512, 0, stream>>>(trans, sctr, emask, W1, W2b, b2, W3b, b3,
                                        lng, lnb, Aw, Bv, Rm, out);
}